// Round 13
// baseline (1934.159 us; speedup 1.0000x reference)
//
#include <hip/hip_runtime.h>
#include <hip/hip_bf16.h>

// ACOPF Gauss-Newton, matrix-free CGLS, single-workgroup LDS-resident solver.
// R13 = R12 (edge/bus split, 4 phases/iter, fp32 reductions, standard PCG,
// 2x2 block-Jacobi, RR-keep-p/64, rel tol 1e-10 + absolute floor) with the
// reduction TAILS software-pipelined against the next phase's LDS loads:
//  - edge-JVP rotated to loop bottom; its fwd/stz/stp loads are issued
//    BEFORE the gamma tail (they don't need beta; only the FMAs do);
//  - edge-VJP's rev/sts loads are issued BEFORE the delta tail.
// Arithmetic bit-identical to R12 (load scheduling only). ~2x200-300 cyc of
// tail latency hidden per iteration out of ~4000.

#define NBUS 1000
#define NLINE 2000
#define NE   (2*NLINE)
#define NGEN 100
#define NLOAD 500
#define NTH 1024
#define NWAVE (NTH/64)
#define MAXSTEPS 10
#define KCG_MAX 600
#define RIDGE_F 1e-6f
#define TOL_REL 1e-10

struct Ws {
  int   vm_pos[NBUS];
  int   va_pos[NBUS];
  float Pspec[NBUS];
  float Qspec[NBUS];
  float Vgb[NBUS];
};

__device__ __forceinline__ float rdf(const void* p, int i, int bf) {
  if (bf) {
    unsigned int u = ((unsigned int)(((const unsigned short*)p)[i])) << 16;
    return __uint_as_float(u);
  }
  return ((const float*)p)[i];
}
__device__ __forceinline__ void wrf(void* p, int i, float v, int bf) {
  if (bf) {
    unsigned int u = __float_as_uint(v);
    unsigned int r = (u + 0x7fffu + ((u >> 16) & 1u)) >> 16;  // RNE
    ((unsigned short*)p)[i] = (unsigned short)r;
  } else {
    ((float*)p)[i] = v;
  }
}
__device__ __forceinline__ int detect_bf(const void* p) {
  const unsigned short* h = (const unsigned short*)p;
  int ok = 1;
#pragma unroll
  for (int i = 0; i < 8; ++i) {
    float v = __uint_as_float(((unsigned int)h[i]) << 16);
    ok &= (v > 0.25f && v < 8.0f) ? 1 : 0;
  }
  return ok;
}
__device__ __forceinline__ int lbound(const int* a, int n, int v) {
  int lo = 0, hi = n;
  while (lo < hi) { int m = (lo + hi) >> 1; if (a[m] < v) lo = m + 1; else hi = m; }
  return lo;
}

struct In {
  const void *lg, *lb, *tp, *sh, *ch;
  const int *lf, *lt;
  int bf;
};
struct LineY { int f, t; float ffr, ffi, ttr, tti, ftr, fti, tfr, tfi; };

__device__ __forceinline__ LineY line_y(const In& I, int l) {
  LineY L;
  float g = rdf(I.lg, l, I.bf), b = rdf(I.lb, l, I.bf);
  float t = rdf(I.tp, l, I.bf), s = rdf(I.sh, l, I.bf);
  float c = rdf(I.ch, l, I.bf) * 0.5f;
  float sn, cs;
  __sincosf(s, &sn, &cs);
  float it = 1.0f / t, it2 = it * it;
  L.f = I.lf[l]; L.t = I.lt[l];
  L.ffr = g * it2;                 L.ffi = (b + c) * it2;
  L.ttr = g;                       L.tti = b + c;
  L.ftr = -(g * cs - b * sn) * it; L.fti = -(g * sn + b * cs) * it;
  L.tfr = -(g * cs + b * sn) * it; L.tfi = -(b * cs - g * sn) * it;
  return L;
}

// wave partial: 6-shuffle reduce, wave partials to LDS (no tail)
__device__ __forceinline__ void wave_part(float v, float* red) {
#pragma unroll
  for (int o = 32; o > 0; o >>= 1) v += __shfl_down(v, o, 64);
  if ((threadIdx.x & 63) == 0) red[threadIdx.x >> 6] = v;
}
// tail: 4 independent float4 reads, same summation order as R12
__device__ __forceinline__ float red_tail(const float* red) {
  const float4* r4 = (const float4*)red;
  float s = 0.f;
#pragma unroll
  for (int w = 0; w < NWAVE / 4; ++w) {
    float4 t = r4[w];
    s += t.x; s += t.y; s += t.z; s += t.w;
  }
  return s;
}
__device__ __forceinline__ float blk_sumf(float v, float* red) {
  wave_part(v, red);
  __syncthreads();
  return red_tail(red);
}

__global__ void setup_k(const void* lg, const void* Pg, const void* Vg,
                        const void* Pl, const void* Ql,
                        const int* gen_b, const int* load_b, const int* refp,
                        Ws* __restrict__ W) {
  int bf = detect_bf(lg);
  int t = blockIdx.x * blockDim.x + threadIdx.x;
  int ref = refp[0];
  if (t < NBUS) {
    int gl = lbound(gen_b, NGEN, t);
    int isg = (gl < NGEN && gen_b[gl] == t) ? 1 : 0;
    int ll = lbound(load_b, NLOAD, t);
    int isl = (ll < NLOAD && load_b[ll] == t) ? 1 : 0;
    W->vm_pos[t] = isg ? -1 : (t - gl);
    W->va_pos[t] = (t == ref) ? -1 : (t - ((t > ref) ? 1 : 0));
    float ps = 0.f, qs = 0.f;
    if (isg) ps += rdf(Pg, gl, bf);
    if (isl) { ps += rdf(Pl, ll, bf); qs += rdf(Ql, ll, bf); }
    W->Pspec[t] = ps;
    W->Qspec[t] = qs;
    W->Vgb[t] = isg ? rdf(Vg, gl, bf) : 1.0f;
  }
}

__global__ void __launch_bounds__(NTH)
solver_k(const void* lg, const void* lb, const void* shg, const void* shb,
         const void* tp, const void* sh, const void* ch, const void* limits,
         const int* lf, const int* lt, const int* gen_b, const int* refp,
         const Ws* __restrict__ W, void* __restrict__ out) {
  __shared__ int rs_[NBUS + 1];
  __shared__ unsigned short cidx_[NE];  // edge -> source-bus index
  __shared__ float2 fwd_[NE];           // Y_kj for edge in row k
  __shared__ float2 rev_[NE];           // Y_jk
  __shared__ float2 ev_[NE];            // per-edge values (overlaid at setup)
  __shared__ float2 stp_[NBUS];         // T(p_{k-1}) per bus
  __shared__ float2 stz_[NBUS];         // T(z_k) per bus
  __shared__ float2 sts_[NBUS];         // seed staging (q seeds / RR / outer)
  __shared__ float2 ab_[NBUS];          // per-bus V (re,im)
  __shared__ float2 mk_[NBUS];          // (mnr, mng)
  __shared__ float2 gb_[NBUS];          // diag Y_kk
  __shared__ __align__(16) float red_[2][NWAVE];

  const int tid = threadIdx.x;
  const bool own = (tid < NBUS);
  In I;
  I.lg = lg; I.lb = lb; I.tp = tp; I.sh = sh; I.ch = ch;
  I.lf = lf; I.lt = lt;
  I.bf = detect_bf(lg);
  const int bf = I.bf;

  // setup scratch overlaid on ev_
  int* scanA = (int*)ev_;
  int* scanB = ((int*)ev_) + NTH;
  int* cur_  = ((int*)ev_) + 2 * NTH;

  int vp = -1, ap = -1;
  float mng = 0.f, mnr = 0.f, Pspec = 0.f, Qspec = 0.f, Vgb = 1.f;
  if (own) {
    vp = W->vm_pos[tid]; ap = W->va_pos[tid];
    mng = (vp >= 0) ? 1.f : 0.f;
    mnr = (ap >= 0) ? 1.f : 0.f;
    Pspec = W->Pspec[tid]; Qspec = W->Qspec[tid]; Vgb = W->Vgb[tid];
    mk_[tid] = make_float2(mnr, mng);
    gb_[tid] = make_float2(rdf(shg, tid, bf), rdf(shb, tid, bf));
  }
  scanA[tid] = 0;
  __syncthreads();
  for (int l = tid; l < NLINE; l += NTH) {
    atomicAdd(&scanA[lf[l]], 1);
    atomicAdd(&scanA[lt[l]], 1);
  }
  __syncthreads();
  {
    int* src = scanA; int* dst = scanB;
    for (int off = 1; off < NTH; off <<= 1) {
      int v = src[tid] + ((tid >= off) ? src[tid - off] : 0);
      dst[tid] = v;
      __syncthreads();
      int* t = src; src = dst; dst = t;
    }
    if (tid == 0) rs_[0] = 0;
    if (own) rs_[tid + 1] = src[tid];
  }
  __syncthreads();
  if (own) cur_[tid] = rs_[tid];
  __syncthreads();
  for (int l = tid; l < NLINE; l += NTH) {
    LineY L = line_y(I, l);
    int pf = atomicAdd(&cur_[L.f], 1);
    cidx_[pf] = (unsigned short)L.t;
    fwd_[pf] = make_float2(L.ftr, L.fti);
    rev_[pf] = make_float2(L.tfr, L.tfi);
    int pt = atomicAdd(&cur_[L.t], 1);
    cidx_[pt] = (unsigned short)L.f;
    fwd_[pt] = make_float2(L.tfr, L.tfi);
    rev_[pt] = make_float2(L.ftr, L.fti);
    atomicAdd(&gb_[L.f].x, L.ffr); atomicAdd(&gb_[L.f].y, L.ffi);
    atomicAdd(&gb_[L.t].x, L.ttr); atomicAdd(&gb_[L.t].y, L.tti);
  }
  __syncthreads();
  float Gkk = 0.f, Bkk = 0.f;
  int rs0 = 0, rs1 = 0;
  if (own) { Gkk = gb_[tid].x; Bkk = gb_[tid].y; rs0 = rs_[tid]; rs1 = rs_[tid + 1]; }
  __syncthreads();   // cur_ overlay dead; ev_ free for edge values

  #define EDGE_JVP_S(SRC) \
    for (int k = 0; k < 4; ++k) { \
      int e = tid + k * NTH; \
      if (e < NE) { \
        int j = cidx_[e]; float2 f = fwd_[e], v = SRC[j]; \
        ev_[e] = make_float2(f.x * v.x - f.y * v.y, f.x * v.y + f.y * v.x); \
      } \
    }
  #define EDGE_VJP(SRC) \
    for (int k = 0; k < 4; ++k) { \
      int e = tid + k * NTH; \
      if (e < NE) { \
        int j = cidx_[e]; float2 r = rev_[e], w = SRC[j]; \
        ev_[e] = make_float2(r.x * w.x + r.y * w.y, r.x * w.y - r.y * w.x); \
      } \
    }
  #define EDGE_JVP_P() \
    for (int k = 0; k < 4; ++k) { \
      int e = tid + k * NTH; \
      if (e < NE) { \
        int j = cidx_[e]; float2 f = fwd_[e], vz = stz_[j], vq = stp_[j]; \
        float vx = vz.x + beta * vq.x, vy = vz.y + beta * vq.y; \
        ev_[e] = make_float2(f.x * vx - f.y * vy, f.x * vy + f.y * vx); \
      } \
    }

  float xvm = 1.f, xva = 0.f;
  int par = 0;
  double gabs = 0.0;   // absolute stopping floor, set from step 0's gamma0

  for (int outer = 0; outer < MAXSTEPS; ++outer) {
    // A: stage V
    float av = 0.f, bv = 0.f, ca = 1.f, sa = 0.f;
    if (own) {
      float Vm = (vp >= 0) ? xvm : Vgb;
      float Va = (ap >= 0) ? xva : 0.f;
      __sincosf(Va, &sa, &ca);
      av = Vm * ca; bv = Vm * sa;
      ab_[tid] = make_float2(av, bv);
    }
    __syncthreads();
    // B: edge products of I = Y V
    EDGE_JVP_S(ab_)
    __syncthreads();
    // C: currents, residual, Gram 2x2, stage g0 seeds
    float cI = 0.f, dI = 0.f, wPp = 0.f, wQq = 0.f;
    float M11 = 0.f, M12 = 0.f, M22 = 0.f;
    if (own) {
      cI = Gkk * av - Bkk * bv; dI = Gkk * bv + Bkk * av;
      for (int e = rs0; e < rs1; ++e) { float2 v = ev_[e]; cI += v.x; dI += v.y; }
      float P = av * cI + bv * dI - Pspec;
      float Q = bv * cI - av * dI - Qspec;
      wPp = mnr * P; wQq = mng * Q;
      sts_[tid] = make_float2(wPp * av + wQq * bv, wPp * bv - wQq * av);
      float w1r = ca * cI + sa * dI, w1i = sa * cI - ca * dI;
      float mr = Gkk * ca - Bkk * sa, mi = -(Gkk * sa + Bkk * ca);
      float ur0 = av * mr - bv * mi, ui0 = av * mi + bv * mr;
      float Tr = w1r + ur0, Ti = w1i + ui0;
      float w2r = av * dI - bv * cI, w2i = av * cI + bv * dI;
      float wr0 = Gkk * av - Bkk * bv, wi0 = Gkk * bv + Bkk * av;
      float zr0 = av * wr0 + bv * wi0, zi0 = bv * wr0 - av * wi0;
      float Uor = w2r + zi0, Uoi = w2i - zr0;
      float Avv = mnr * Tr * Tr + mng * Ti * Ti;
      float Aaa = mnr * Uor * Uor + mng * Uoi * Uoi;
      float Ava = mnr * Tr * Uor + mng * Ti * Uoi;
      for (int e = rs0; e < rs1; ++e) {
        int j = cidx_[e]; float2 r = rev_[e], vj = ab_[j], mj = mk_[j];
        float mrr = r.x * ca - r.y * sa, mii = -(r.x * sa + r.y * ca);
        float ur = vj.x * mrr - vj.y * mii, ui = vj.x * mii + vj.y * mrr;
        float wr = r.x * av - r.y * bv, wi = r.x * bv + r.y * av;
        float zr = vj.x * wr + vj.y * wi, zi = vj.y * wr - vj.x * wi;
        Avv += mj.x * ur * ur + mj.y * ui * ui;
        Aaa += mj.x * zi * zi + mj.y * zr * zr;
        Ava += mj.x * ur * zi - mj.y * ui * zr;
      }
      float A11 = Avv + RIDGE_F, A22 = Aaa + RIDGE_F;
      if (vp >= 0 && ap >= 0) {
        float id = 1.f / (A11 * A22 - Ava * Ava);
        M11 = A22 * id; M22 = A11 * id; M12 = -Ava * id;
      } else if (vp >= 0) M11 = 1.f / A11;
      else if (ap >= 0)  M22 = 1.f / A22;
    }
    __syncthreads();
    // D: edge-VJP of g0
    EDGE_VJP(sts_)
    __syncthreads();
    // E: g0, PCG init, stage T(z0), stp=0, beta=0
    float g0vm = 0.f, g0va = 0.f;
    if (own) {
      float cb = wPp * av + wQq * bv, db2 = wPp * bv - wQq * av;
      float sda = wPp * cI - wQq * dI + Gkk * cb + Bkk * db2;
      float sdb = wPp * dI + wQq * cI - Bkk * cb + Gkk * db2;
      for (int e = rs0; e < rs1; ++e) { float2 v = ev_[e]; sda += v.x; sdb += v.y; }
      g0vm = mng * (ca * sda + sa * sdb);
      g0va = mnr * (-bv * sda + av * sdb);
    }
    float rvm = g0vm, rva = g0va, dxvm = 0.f, dxva = 0.f;
    float zvm = M11 * rvm + M12 * rva, zva = M12 * rvm + M22 * rva;
    float pvm = 0.f, pva = 0.f;          // p enters loop as z + beta*p, beta=0
    float tzx = 0.f, tzy = 0.f, tpx = 0.f, tpy = 0.f;
    float beta = 0.f;
    if (own) {
      tzx = zvm * ca - zva * bv; tzy = zvm * sa + zva * av;
      stz_[tid] = make_float2(tzx, tzy);
      stp_[tid] = make_float2(0.f, 0.f);
    }
    float part = own ? (rvm * zvm + rva * zva) : 0.f;
    double gamma = (double)blk_sumf(part, red_[par]); par ^= 1;  // fences staging
    const double gamma0 = gamma;
    if (outer == 0) gabs = 0.1 * TOL_REL * gamma0;
    const double thr = fmax(gamma0 * TOL_REL, gabs);

    if (gamma0 > thr) {
      // prologue: first edge-JVP of p_1 = z_0 (beta = 0)
      EDGE_JVP_P()
      __syncthreads();
      for (int it = 0; it < KCG_MAX; ++it) {
        // X: refresh p / T(p), rowsum, q seeds, delta partial
        float qP = 0.f, qQ = 0.f;
        float dpart = 0.f;
        if (own) {
          pvm = zvm + beta * pvm; pva = zva + beta * pva;
          tpx = tzx + beta * tpx; tpy = tzy + beta * tpy;
          stp_[tid] = make_float2(tpx, tpy);
          float dc = Gkk * tpx - Bkk * tpy, dd = Gkk * tpy + Bkk * tpx;
          for (int e = rs0; e < rs1; ++e) { float2 v = ev_[e]; dc += v.x; dd += v.y; }
          float dP = tpx * cI + av * dc + tpy * dI + bv * dd;
          float dQ = tpy * cI + bv * dc - tpx * dI - av * dd;
          qP = mnr * dP; qQ = mng * dQ;
          sts_[tid] = make_float2(qP * av + qQ * bv, qP * bv - qQ * av);
          dpart = qP * dP + qQ * dQ + RIDGE_F * (pvm * pvm + pva * pva);
        }
        wave_part(dpart, red_[par]);
        __syncthreads();
        // Y: preload VJP operands (independent of delta), THEN tail, then write
        float2 rr[4], ww[4];
#pragma unroll
        for (int k = 0; k < 4; ++k) {
          int e = tid + k * NTH;
          if (e < NE) { rr[k] = rev_[e]; ww[k] = sts_[cidx_[e]]; }
        }
        double delta = (double)red_tail(red_[par]); par ^= 1;
        if (!(delta > 0.0)) break;
        float af = (float)(gamma / delta);
#pragma unroll
        for (int k = 0; k < 4; ++k) {
          int e = tid + k * NTH;
          if (e < NE)
            ev_[e] = make_float2(rr[k].x * ww[k].x + rr[k].y * ww[k].y,
                                 rr[k].x * ww[k].y - rr[k].y * ww[k].x);
        }
        __syncthreads();
        // Z: rowsum, r/dx update, (RR), z, stage T(z), gamma partial
        if (own) {
          dxvm += af * pvm; dxva += af * pva;
          float cb = qP * av + qQ * bv, db2 = qP * bv - qQ * av;
          float sda = qP * cI - qQ * dI + Gkk * cb + Bkk * db2;
          float sdb = qP * dI + qQ * cI - Bkk * cb + Gkk * db2;
          for (int e = rs0; e < rs1; ++e) { float2 v = ev_[e]; sda += v.x; sdb += v.y; }
          float yvm = mng * (ca * sda + sa * sdb);
          float yva = mnr * (-bv * sda + av * sdb);
          rvm -= af * (yvm + RIDGE_F * pvm);
          rva -= af * (yva + RIDGE_F * pva);
        }
        if ((it & 63) == 63) {
          // residual replacement: r = g0 - (A + ridge) dx  (keep p)
          float tda = 0.f, tdb = 0.f;
          if (own) {
            tda = dxvm * ca - dxva * bv;
            tdb = dxvm * sa + dxva * av;
            sts_[tid] = make_float2(tda, tdb);
          }
          __syncthreads();   // all Z rowsum reads of ev_ done
          EDGE_JVP_S(sts_)
          __syncthreads();
          float rqP = 0.f, rqQ = 0.f;
          if (own) {
            float dc = Gkk * tda - Bkk * tdb, dd = Gkk * tdb + Bkk * tda;
            for (int e = rs0; e < rs1; ++e) { float2 v = ev_[e]; dc += v.x; dd += v.y; }
            float dP = tda * cI + av * dc + tdb * dI + bv * dd;
            float dQ = tdb * cI + bv * dc - tda * dI - av * dd;
            rqP = mnr * dP; rqQ = mng * dQ;
            sts_[tid] = make_float2(rqP * av + rqQ * bv, rqP * bv - rqQ * av);
          }
          __syncthreads();
          EDGE_VJP(sts_)
          __syncthreads();
          if (own) {
            float cb = rqP * av + rqQ * bv, db2 = rqP * bv - rqQ * av;
            float sda = rqP * cI - rqQ * dI + Gkk * cb + Bkk * db2;
            float sdb = rqP * dI + rqQ * cI - Bkk * cb + Gkk * db2;
            for (int e = rs0; e < rs1; ++e) { float2 v = ev_[e]; sda += v.x; sdb += v.y; }
            float tvm = mng * (ca * sda + sa * sdb);
            float tva = mnr * (-bv * sda + av * sdb);
            rvm = g0vm - tvm - RIDGE_F * dxvm;
            rva = g0va - tva - RIDGE_F * dxva;
          }
        }
        float gpart = 0.f;
        if (own) {
          zvm = M11 * rvm + M12 * rva; zva = M12 * rvm + M22 * rva;
          tzx = zvm * ca - zva * bv; tzy = zvm * sa + zva * av;
          stz_[tid] = make_float2(tzx, tzy);
          gpart = rvm * zvm + rva * zva;
        }
        wave_part(gpart, red_[par]);
        __syncthreads();   // fences stz_/stp_ and red_
        // bottom: preload next JVP operands (independent of beta), THEN tail
        float2 ff[4], vz[4], vq[4];
#pragma unroll
        for (int k = 0; k < 4; ++k) {
          int e = tid + k * NTH;
          if (e < NE) {
            int j = cidx_[e];
            ff[k] = fwd_[e]; vz[k] = stz_[j]; vq[k] = stp_[j];
          }
        }
        double gamma2 = (double)red_tail(red_[par]); par ^= 1;
        if (gamma2 <= thr || !(gamma2 > 0.0)) break;
        beta = (float)(gamma2 / gamma);
        gamma = gamma2;
#pragma unroll
        for (int k = 0; k < 4; ++k) {
          int e = tid + k * NTH;
          if (e < NE) {
            float vx = vz[k].x + beta * vq[k].x, vy = vz[k].y + beta * vq[k].y;
            ev_[e] = make_float2(ff[k].x * vx - ff[k].y * vy,
                                 ff[k].x * vy + ff[k].y * vx);
          }
        }
        __syncthreads();   // fences ev_ for next X
      }
    }
    if (own) { xvm -= dxvm; xva -= dxva; }
    __syncthreads();
  }

  // ---- final outputs ----
  float Vmf = 1.f, Vaf = 0.f, av = 0.f, bv = 0.f, cI = 0.f, dI = 0.f;
  if (own) {
    Vmf = (vp >= 0) ? xvm : Vgb;
    Vaf = (ap >= 0) ? xva : 0.f;
    float sn, cs;
    __sincosf(Vaf, &sn, &cs);
    av = Vmf * cs; bv = Vmf * sn;
    ab_[tid] = make_float2(av, bv);
  }
  __syncthreads();
  EDGE_JVP_S(ab_)
  __syncthreads();
  float P = 0.f, Q = 0.f;
  if (own) {
    cI = Gkk * av - Bkk * bv; dI = Gkk * bv + Bkk * av;
    for (int e = rs0; e < rs1; ++e) { float2 v = ev_[e]; cI += v.x; dI += v.y; }
    P = av * cI + bv * dI - Pspec;
    Q = bv * cI - av * dI - Qspec;
    sts_[tid] = make_float2(P, Q);
  }
  __syncthreads();
  float rpart = own ? (mnr * P * P + mng * Q * Q) : 0.f;
  float rsum = blk_sumf(rpart, red_[par]); par ^= 1;
  if (own) {
    wrf(out, tid, Vmf, bf);
    wrf(out, NBUS + tid, Vaf, bf);
    float vmin = rdf(limits, 2 * tid, bf), vmax = rdf(limits, 2 * tid + 1, bf);
    float viol = fmaxf(Vmf - vmax, 0.f) + fmaxf(vmin - Vmf, 0.f);
    wrf(out, 2103 + tid, viol, bf);
  }
  if (tid < NGEN) wrf(out, 2000 + tid, sts_[gen_b[tid]].y, bf);
  if (tid == 0) {
    int ref = refp[0];
    wrf(out, 2100, sts_[ref].x, bf);
    wrf(out, 2101, sts_[ref].y, bf);
    wrf(out, 2102, rsum, bf);
  }
}

extern "C" void kernel_launch(void* const* d_in, const int* in_sizes, int n_in,
                              void* d_out, int out_size, void* d_ws, size_t ws_size,
                              hipStream_t stream) {
  const void* line_g   = d_in[0];
  const void* line_b   = d_in[1];
  const void* shunt_g  = d_in[2];
  const void* shunt_b  = d_in[3];
  const void* tap      = d_in[4];
  const void* shift    = d_in[5];
  const void* charging = d_in[6];
  const void* P_gen    = d_in[7];
  const void* V_gen    = d_in[8];
  const void* P_load   = d_in[9];
  const void* Q_load   = d_in[10];
  const void* limits   = d_in[11];
  const int* line_from = (const int*)d_in[12];
  const int* line_to   = (const int*)d_in[13];
  const int* gen_b     = (const int*)d_in[14];
  const int* load_b    = (const int*)d_in[15];
  const int* refp      = (const int*)d_in[18];

  if (ws_size < sizeof(Ws)) return;
  Ws* W = (Ws*)d_ws;

  setup_k<<<dim3(8), dim3(256), 0, stream>>>(line_g, P_gen, V_gen, P_load, Q_load,
                                             gen_b, load_b, refp, W);
  solver_k<<<dim3(1), dim3(NTH), 0, stream>>>(line_g, line_b, shunt_g, shunt_b,
                                              tap, shift, charging, limits,
                                              line_from, line_to, gen_b, refp,
                                              W, d_out);
}

// Round 14
// 1871.363 us; speedup vs baseline: 1.0336x; 1.0336x over previous
//
#include <hip/hip_runtime.h>
#include <hip/hip_bf16.h>

// ACOPF Gauss-Newton, matrix-free CGLS, single-workgroup LDS-resident solver.
// R14 = R12 exactly (revert of R13's tail-pipelining, which regressed: DS ops
// complete in-order per wave, so reduction-tail reads issued after preloaded
// gather reads must drain the whole queue — preloads joined the critical path).
// Structure: edge/bus split, 4 phases/iter, fp32 reductions, standard PCG,
// 2x2 block-Jacobi, RR-keep-p/64, rel tol 1e-10 + absolute floor
// 0.1*1e-10*gamma0_step0. Best measured: 1875 us, absmax 0.1875.

#define NBUS 1000
#define NLINE 2000
#define NE   (2*NLINE)
#define NGEN 100
#define NLOAD 500
#define NTH 1024
#define NWAVE (NTH/64)
#define MAXSTEPS 10
#define KCG_MAX 600
#define RIDGE_F 1e-6f
#define TOL_REL 1e-10

struct Ws {
  int   vm_pos[NBUS];
  int   va_pos[NBUS];
  float Pspec[NBUS];
  float Qspec[NBUS];
  float Vgb[NBUS];
};

__device__ __forceinline__ float rdf(const void* p, int i, int bf) {
  if (bf) {
    unsigned int u = ((unsigned int)(((const unsigned short*)p)[i])) << 16;
    return __uint_as_float(u);
  }
  return ((const float*)p)[i];
}
__device__ __forceinline__ void wrf(void* p, int i, float v, int bf) {
  if (bf) {
    unsigned int u = __float_as_uint(v);
    unsigned int r = (u + 0x7fffu + ((u >> 16) & 1u)) >> 16;  // RNE
    ((unsigned short*)p)[i] = (unsigned short)r;
  } else {
    ((float*)p)[i] = v;
  }
}
__device__ __forceinline__ int detect_bf(const void* p) {
  const unsigned short* h = (const unsigned short*)p;
  int ok = 1;
#pragma unroll
  for (int i = 0; i < 8; ++i) {
    float v = __uint_as_float(((unsigned int)h[i]) << 16);
    ok &= (v > 0.25f && v < 8.0f) ? 1 : 0;
  }
  return ok;
}
__device__ __forceinline__ int lbound(const int* a, int n, int v) {
  int lo = 0, hi = n;
  while (lo < hi) { int m = (lo + hi) >> 1; if (a[m] < v) lo = m + 1; else hi = m; }
  return lo;
}

struct In {
  const void *lg, *lb, *tp, *sh, *ch;
  const int *lf, *lt;
  int bf;
};
struct LineY { int f, t; float ffr, ffi, ttr, tti, ftr, fti, tfr, tfi; };

__device__ __forceinline__ LineY line_y(const In& I, int l) {
  LineY L;
  float g = rdf(I.lg, l, I.bf), b = rdf(I.lb, l, I.bf);
  float t = rdf(I.tp, l, I.bf), s = rdf(I.sh, l, I.bf);
  float c = rdf(I.ch, l, I.bf) * 0.5f;
  float sn, cs;
  __sincosf(s, &sn, &cs);
  float it = 1.0f / t, it2 = it * it;
  L.f = I.lf[l]; L.t = I.lt[l];
  L.ffr = g * it2;                 L.ffi = (b + c) * it2;
  L.ttr = g;                       L.tti = b + c;
  L.ftr = -(g * cs - b * sn) * it; L.fti = -(g * sn + b * cs) * it;
  L.tfr = -(g * cs + b * sn) * it; L.tfi = -(b * cs - g * sn) * it;
  return L;
}

// fp32 block sum: 6-shuffle wave reduce, wave partials to LDS, tail = 4
// independent float4 reads. (Shuffle-tree tails and preloaded-tail pipelining
// both regressed — DS dependent chains / in-order completion.)
__device__ __forceinline__ float blk_sumf(float v, float* red) {
#pragma unroll
  for (int o = 32; o > 0; o >>= 1) v += __shfl_down(v, o, 64);
  if ((threadIdx.x & 63) == 0) red[threadIdx.x >> 6] = v;
  __syncthreads();
  const float4* r4 = (const float4*)red;
  float s = 0.f;
#pragma unroll
  for (int w = 0; w < NWAVE / 4; ++w) {
    float4 t = r4[w];
    s += t.x; s += t.y; s += t.z; s += t.w;
  }
  return s;
}

__global__ void setup_k(const void* lg, const void* Pg, const void* Vg,
                        const void* Pl, const void* Ql,
                        const int* gen_b, const int* load_b, const int* refp,
                        Ws* __restrict__ W) {
  int bf = detect_bf(lg);
  int t = blockIdx.x * blockDim.x + threadIdx.x;
  int ref = refp[0];
  if (t < NBUS) {
    int gl = lbound(gen_b, NGEN, t);
    int isg = (gl < NGEN && gen_b[gl] == t) ? 1 : 0;
    int ll = lbound(load_b, NLOAD, t);
    int isl = (ll < NLOAD && load_b[ll] == t) ? 1 : 0;
    W->vm_pos[t] = isg ? -1 : (t - gl);
    W->va_pos[t] = (t == ref) ? -1 : (t - ((t > ref) ? 1 : 0));
    float ps = 0.f, qs = 0.f;
    if (isg) ps += rdf(Pg, gl, bf);
    if (isl) { ps += rdf(Pl, ll, bf); qs += rdf(Ql, ll, bf); }
    W->Pspec[t] = ps;
    W->Qspec[t] = qs;
    W->Vgb[t] = isg ? rdf(Vg, gl, bf) : 1.0f;
  }
}

__global__ void __launch_bounds__(NTH)
solver_k(const void* lg, const void* lb, const void* shg, const void* shb,
         const void* tp, const void* sh, const void* ch, const void* limits,
         const int* lf, const int* lt, const int* gen_b, const int* refp,
         const Ws* __restrict__ W, void* __restrict__ out) {
  __shared__ int rs_[NBUS + 1];
  __shared__ unsigned short cidx_[NE];  // edge -> source-bus index
  __shared__ float2 fwd_[NE];           // Y_kj for edge in row k
  __shared__ float2 rev_[NE];           // Y_jk
  __shared__ float2 ev_[NE];            // per-edge values (overlaid at setup)
  __shared__ float2 stp_[NBUS];         // T(p_{k-1}) per bus
  __shared__ float2 stz_[NBUS];         // T(z_k) per bus
  __shared__ float2 sts_[NBUS];         // seed staging (q seeds / RR / outer)
  __shared__ float2 ab_[NBUS];          // per-bus V (re,im)
  __shared__ float2 mk_[NBUS];          // (mnr, mng)
  __shared__ float2 gb_[NBUS];          // diag Y_kk
  __shared__ __align__(16) float red_[2][NWAVE];

  const int tid = threadIdx.x;
  const bool own = (tid < NBUS);
  In I;
  I.lg = lg; I.lb = lb; I.tp = tp; I.sh = sh; I.ch = ch;
  I.lf = lf; I.lt = lt;
  I.bf = detect_bf(lg);
  const int bf = I.bf;

  // setup scratch overlaid on ev_
  int* scanA = (int*)ev_;
  int* scanB = ((int*)ev_) + NTH;
  int* cur_  = ((int*)ev_) + 2 * NTH;

  int vp = -1, ap = -1;
  float mng = 0.f, mnr = 0.f, Pspec = 0.f, Qspec = 0.f, Vgb = 1.f;
  if (own) {
    vp = W->vm_pos[tid]; ap = W->va_pos[tid];
    mng = (vp >= 0) ? 1.f : 0.f;
    mnr = (ap >= 0) ? 1.f : 0.f;
    Pspec = W->Pspec[tid]; Qspec = W->Qspec[tid]; Vgb = W->Vgb[tid];
    mk_[tid] = make_float2(mnr, mng);
    gb_[tid] = make_float2(rdf(shg, tid, bf), rdf(shb, tid, bf));
  }
  scanA[tid] = 0;
  __syncthreads();
  for (int l = tid; l < NLINE; l += NTH) {
    atomicAdd(&scanA[lf[l]], 1);
    atomicAdd(&scanA[lt[l]], 1);
  }
  __syncthreads();
  {
    int* src = scanA; int* dst = scanB;
    for (int off = 1; off < NTH; off <<= 1) {
      int v = src[tid] + ((tid >= off) ? src[tid - off] : 0);
      dst[tid] = v;
      __syncthreads();
      int* t = src; src = dst; dst = t;
    }
    if (tid == 0) rs_[0] = 0;
    if (own) rs_[tid + 1] = src[tid];
  }
  __syncthreads();
  if (own) cur_[tid] = rs_[tid];
  __syncthreads();
  for (int l = tid; l < NLINE; l += NTH) {
    LineY L = line_y(I, l);
    int pf = atomicAdd(&cur_[L.f], 1);
    cidx_[pf] = (unsigned short)L.t;
    fwd_[pf] = make_float2(L.ftr, L.fti);
    rev_[pf] = make_float2(L.tfr, L.tfi);
    int pt = atomicAdd(&cur_[L.t], 1);
    cidx_[pt] = (unsigned short)L.f;
    fwd_[pt] = make_float2(L.tfr, L.tfi);
    rev_[pt] = make_float2(L.ftr, L.fti);
    atomicAdd(&gb_[L.f].x, L.ffr); atomicAdd(&gb_[L.f].y, L.ffi);
    atomicAdd(&gb_[L.t].x, L.ttr); atomicAdd(&gb_[L.t].y, L.tti);
  }
  __syncthreads();
  float Gkk = 0.f, Bkk = 0.f;
  int rs0 = 0, rs1 = 0;
  if (own) { Gkk = gb_[tid].x; Bkk = gb_[tid].y; rs0 = rs_[tid]; rs1 = rs_[tid + 1]; }
  __syncthreads();   // cur_ overlay dead; ev_ free for edge values

  #define EDGE_JVP_S(SRC) \
    for (int k = 0; k < 4; ++k) { \
      int e = tid + k * NTH; \
      if (e < NE) { \
        int j = cidx_[e]; float2 f = fwd_[e], v = SRC[j]; \
        ev_[e] = make_float2(f.x * v.x - f.y * v.y, f.x * v.y + f.y * v.x); \
      } \
    }
  #define EDGE_VJP(SRC) \
    for (int k = 0; k < 4; ++k) { \
      int e = tid + k * NTH; \
      if (e < NE) { \
        int j = cidx_[e]; float2 r = rev_[e], w = SRC[j]; \
        ev_[e] = make_float2(r.x * w.x + r.y * w.y, r.x * w.y - r.y * w.x); \
      } \
    }
  #define EDGE_JVP_P() \
    for (int k = 0; k < 4; ++k) { \
      int e = tid + k * NTH; \
      if (e < NE) { \
        int j = cidx_[e]; float2 f = fwd_[e], vz = stz_[j], vq = stp_[j]; \
        float vx = vz.x + beta * vq.x, vy = vz.y + beta * vq.y; \
        ev_[e] = make_float2(f.x * vx - f.y * vy, f.x * vy + f.y * vx); \
      } \
    }

  float xvm = 1.f, xva = 0.f;
  int par = 0;
  double gabs = 0.0;   // absolute stopping floor, set from step 0's gamma0

  for (int outer = 0; outer < MAXSTEPS; ++outer) {
    // A: stage V
    float av = 0.f, bv = 0.f, ca = 1.f, sa = 0.f;
    if (own) {
      float Vm = (vp >= 0) ? xvm : Vgb;
      float Va = (ap >= 0) ? xva : 0.f;
      __sincosf(Va, &sa, &ca);
      av = Vm * ca; bv = Vm * sa;
      ab_[tid] = make_float2(av, bv);
    }
    __syncthreads();
    // B: edge products of I = Y V
    EDGE_JVP_S(ab_)
    __syncthreads();
    // C: currents, residual, Gram 2x2, stage g0 seeds
    float cI = 0.f, dI = 0.f, wPp = 0.f, wQq = 0.f;
    float M11 = 0.f, M12 = 0.f, M22 = 0.f;
    if (own) {
      cI = Gkk * av - Bkk * bv; dI = Gkk * bv + Bkk * av;
      for (int e = rs0; e < rs1; ++e) { float2 v = ev_[e]; cI += v.x; dI += v.y; }
      float P = av * cI + bv * dI - Pspec;
      float Q = bv * cI - av * dI - Qspec;
      wPp = mnr * P; wQq = mng * Q;
      sts_[tid] = make_float2(wPp * av + wQq * bv, wPp * bv - wQq * av);
      float w1r = ca * cI + sa * dI, w1i = sa * cI - ca * dI;
      float mr = Gkk * ca - Bkk * sa, mi = -(Gkk * sa + Bkk * ca);
      float ur0 = av * mr - bv * mi, ui0 = av * mi + bv * mr;
      float Tr = w1r + ur0, Ti = w1i + ui0;
      float w2r = av * dI - bv * cI, w2i = av * cI + bv * dI;
      float wr0 = Gkk * av - Bkk * bv, wi0 = Gkk * bv + Bkk * av;
      float zr0 = av * wr0 + bv * wi0, zi0 = bv * wr0 - av * wi0;
      float Uor = w2r + zi0, Uoi = w2i - zr0;
      float Avv = mnr * Tr * Tr + mng * Ti * Ti;
      float Aaa = mnr * Uor * Uor + mng * Uoi * Uoi;
      float Ava = mnr * Tr * Uor + mng * Ti * Uoi;
      for (int e = rs0; e < rs1; ++e) {
        int j = cidx_[e]; float2 r = rev_[e], vj = ab_[j], mj = mk_[j];
        float mrr = r.x * ca - r.y * sa, mii = -(r.x * sa + r.y * ca);
        float ur = vj.x * mrr - vj.y * mii, ui = vj.x * mii + vj.y * mrr;
        float wr = r.x * av - r.y * bv, wi = r.x * bv + r.y * av;
        float zr = vj.x * wr + vj.y * wi, zi = vj.y * wr - vj.x * wi;
        Avv += mj.x * ur * ur + mj.y * ui * ui;
        Aaa += mj.x * zi * zi + mj.y * zr * zr;
        Ava += mj.x * ur * zi - mj.y * ui * zr;
      }
      float A11 = Avv + RIDGE_F, A22 = Aaa + RIDGE_F;
      if (vp >= 0 && ap >= 0) {
        float id = 1.f / (A11 * A22 - Ava * Ava);
        M11 = A22 * id; M22 = A11 * id; M12 = -Ava * id;
      } else if (vp >= 0) M11 = 1.f / A11;
      else if (ap >= 0)  M22 = 1.f / A22;
    }
    __syncthreads();
    // D: edge-VJP of g0
    EDGE_VJP(sts_)
    __syncthreads();
    // E: g0, PCG init, stage T(z0), stp=0, beta=0
    float g0vm = 0.f, g0va = 0.f;
    if (own) {
      float cb = wPp * av + wQq * bv, db2 = wPp * bv - wQq * av;
      float sda = wPp * cI - wQq * dI + Gkk * cb + Bkk * db2;
      float sdb = wPp * dI + wQq * cI - Bkk * cb + Gkk * db2;
      for (int e = rs0; e < rs1; ++e) { float2 v = ev_[e]; sda += v.x; sdb += v.y; }
      g0vm = mng * (ca * sda + sa * sdb);
      g0va = mnr * (-bv * sda + av * sdb);
    }
    float rvm = g0vm, rva = g0va, dxvm = 0.f, dxva = 0.f;
    float zvm = M11 * rvm + M12 * rva, zva = M12 * rvm + M22 * rva;
    float pvm = 0.f, pva = 0.f;          // p enters loop as z + beta*p, beta=0
    float tzx = 0.f, tzy = 0.f, tpx = 0.f, tpy = 0.f;
    float beta = 0.f;
    if (own) {
      tzx = zvm * ca - zva * bv; tzy = zvm * sa + zva * av;
      stz_[tid] = make_float2(tzx, tzy);
      stp_[tid] = make_float2(0.f, 0.f);
    }
    float part = own ? (rvm * zvm + rva * zva) : 0.f;
    double gamma = (double)blk_sumf(part, red_[par]); par ^= 1;  // fences staging
    const double gamma0 = gamma;
    if (outer == 0) gabs = 0.1 * TOL_REL * gamma0;
    const double thr = fmax(gamma0 * TOL_REL, gabs);

    if (gamma0 > thr) {
      for (int it = 0; it < KCG_MAX; ++it) {
        // I1: edge-JVP of p_k = z_k + beta*p_{k-1} (dual-source)
        EDGE_JVP_P()
        __syncthreads();
        // I2: refresh p / T(p) (old stp reads fenced), rowsum, q seeds, delta
        float qP = 0.f, qQ = 0.f;
        float dpart = 0.f;
        if (own) {
          pvm = zvm + beta * pvm; pva = zva + beta * pva;
          tpx = tzx + beta * tpx; tpy = tzy + beta * tpy;
          stp_[tid] = make_float2(tpx, tpy);
          float dc = Gkk * tpx - Bkk * tpy, dd = Gkk * tpy + Bkk * tpx;
          for (int e = rs0; e < rs1; ++e) { float2 v = ev_[e]; dc += v.x; dd += v.y; }
          float dP = tpx * cI + av * dc + tpy * dI + bv * dd;
          float dQ = tpy * cI + bv * dc - tpx * dI - av * dd;
          qP = mnr * dP; qQ = mng * dQ;
          sts_[tid] = make_float2(qP * av + qQ * bv, qP * bv - qQ * av);
          dpart = qP * dP + qQ * dQ + RIDGE_F * (pvm * pvm + pva * pva);
        }
        double delta = (double)blk_sumf(dpart, red_[par]); par ^= 1;
        if (!(delta > 0.0)) break;
        float af = (float)(gamma / delta);
        // I3: edge-VJP of q
        EDGE_VJP(sts_)
        __syncthreads();
        // I4: rowsum, r/dx update, (RR), z, stage T(z), gamma-reduce
        if (own) {
          dxvm += af * pvm; dxva += af * pva;
          float cb = qP * av + qQ * bv, db2 = qP * bv - qQ * av;
          float sda = qP * cI - qQ * dI + Gkk * cb + Bkk * db2;
          float sdb = qP * dI + qQ * cI - Bkk * cb + Gkk * db2;
          for (int e = rs0; e < rs1; ++e) { float2 v = ev_[e]; sda += v.x; sdb += v.y; }
          float yvm = mng * (ca * sda + sa * sdb);
          float yva = mnr * (-bv * sda + av * sdb);
          rvm -= af * (yvm + RIDGE_F * pvm);
          rva -= af * (yva + RIDGE_F * pva);
        }
        if ((it & 63) == 63) {
          // residual replacement: r = g0 - (A + ridge) dx  (keep p)
          float tda = 0.f, tdb = 0.f;
          if (own) {
            tda = dxvm * ca - dxva * bv;
            tdb = dxvm * sa + dxva * av;
            sts_[tid] = make_float2(tda, tdb);
          }
          __syncthreads();   // all I4 rowsum reads of ev_ done
          EDGE_JVP_S(sts_)
          __syncthreads();
          float rqP = 0.f, rqQ = 0.f;
          if (own) {
            float dc = Gkk * tda - Bkk * tdb, dd = Gkk * tdb + Bkk * tda;
            for (int e = rs0; e < rs1; ++e) { float2 v = ev_[e]; dc += v.x; dd += v.y; }
            float dP = tda * cI + av * dc + tdb * dI + bv * dd;
            float dQ = tdb * cI + bv * dc - tda * dI - av * dd;
            rqP = mnr * dP; rqQ = mng * dQ;
            sts_[tid] = make_float2(rqP * av + rqQ * bv, rqP * bv - rqQ * av);
          }
          __syncthreads();
          EDGE_VJP(sts_)
          __syncthreads();
          if (own) {
            float cb = rqP * av + rqQ * bv, db2 = rqP * bv - rqQ * av;
            float sda = rqP * cI - rqQ * dI + Gkk * cb + Bkk * db2;
            float sdb = rqP * dI + rqQ * cI - Bkk * cb + Gkk * db2;
            for (int e = rs0; e < rs1; ++e) { float2 v = ev_[e]; sda += v.x; sdb += v.y; }
            float tvm = mng * (ca * sda + sa * sdb);
            float tva = mnr * (-bv * sda + av * sdb);
            rvm = g0vm - tvm - RIDGE_F * dxvm;
            rva = g0va - tva - RIDGE_F * dxva;
          }
        }
        float gpart = 0.f;
        if (own) {
          zvm = M11 * rvm + M12 * rva; zva = M12 * rvm + M22 * rva;
          tzx = zvm * ca - zva * bv; tzy = zvm * sa + zva * av;
          stz_[tid] = make_float2(tzx, tzy);
          gpart = rvm * zvm + rva * zva;
        }
        double gamma2 = (double)blk_sumf(gpart, red_[par]); par ^= 1;  // fences stz_
        if (gamma2 <= thr || !(gamma2 > 0.0)) break;
        beta = (float)(gamma2 / gamma);
        gamma = gamma2;
      }
    }
    if (own) { xvm -= dxvm; xva -= dxva; }
    __syncthreads();
  }

  // ---- final outputs ----
  float Vmf = 1.f, Vaf = 0.f, av = 0.f, bv = 0.f, cI = 0.f, dI = 0.f;
  if (own) {
    Vmf = (vp >= 0) ? xvm : Vgb;
    Vaf = (ap >= 0) ? xva : 0.f;
    float sn, cs;
    __sincosf(Vaf, &sn, &cs);
    av = Vmf * cs; bv = Vmf * sn;
    ab_[tid] = make_float2(av, bv);
  }
  __syncthreads();
  EDGE_JVP_S(ab_)
  __syncthreads();
  float P = 0.f, Q = 0.f;
  if (own) {
    cI = Gkk * av - Bkk * bv; dI = Gkk * bv + Bkk * av;
    for (int e = rs0; e < rs1; ++e) { float2 v = ev_[e]; cI += v.x; dI += v.y; }
    P = av * cI + bv * dI - Pspec;
    Q = bv * cI - av * dI - Qspec;
    sts_[tid] = make_float2(P, Q);
  }
  __syncthreads();
  float rpart = own ? (mnr * P * P + mng * Q * Q) : 0.f;
  float rsum = blk_sumf(rpart, red_[par]); par ^= 1;
  if (own) {
    wrf(out, tid, Vmf, bf);
    wrf(out, NBUS + tid, Vaf, bf);
    float vmin = rdf(limits, 2 * tid, bf), vmax = rdf(limits, 2 * tid + 1, bf);
    float viol = fmaxf(Vmf - vmax, 0.f) + fmaxf(vmin - Vmf, 0.f);
    wrf(out, 2103 + tid, viol, bf);
  }
  if (tid < NGEN) wrf(out, 2000 + tid, sts_[gen_b[tid]].y, bf);
  if (tid == 0) {
    int ref = refp[0];
    wrf(out, 2100, sts_[ref].x, bf);
    wrf(out, 2101, sts_[ref].y, bf);
    wrf(out, 2102, rsum, bf);
  }
}

extern "C" void kernel_launch(void* const* d_in, const int* in_sizes, int n_in,
                              void* d_out, int out_size, void* d_ws, size_t ws_size,
                              hipStream_t stream) {
  const void* line_g   = d_in[0];
  const void* line_b   = d_in[1];
  const void* shunt_g  = d_in[2];
  const void* shunt_b  = d_in[3];
  const void* tap      = d_in[4];
  const void* shift    = d_in[5];
  const void* charging = d_in[6];
  const void* P_gen    = d_in[7];
  const void* V_gen    = d_in[8];
  const void* P_load   = d_in[9];
  const void* Q_load   = d_in[10];
  const void* limits   = d_in[11];
  const int* line_from = (const int*)d_in[12];
  const int* line_to   = (const int*)d_in[13];
  const int* gen_b     = (const int*)d_in[14];
  const int* load_b    = (const int*)d_in[15];
  const int* refp      = (const int*)d_in[18];

  if (ws_size < sizeof(Ws)) return;
  Ws* W = (Ws*)d_ws;

  setup_k<<<dim3(8), dim3(256), 0, stream>>>(line_g, P_gen, V_gen, P_load, Q_load,
                                             gen_b, load_b, refp, W);
  solver_k<<<dim3(1), dim3(NTH), 0, stream>>>(line_g, line_b, shunt_g, shunt_b,
                                              tap, shift, charging, limits,
                                              line_from, line_to, gen_b, refp,
                                              W, d_out);
}